// Round 6
// baseline (27.111 us; speedup 1.0000x reference)
//
#include <hip/hip_runtime.h>
#include <math.h>

#define EPSN 1e-12f

typedef __attribute__((ext_vector_type(8))) __bf16 bf16x8;
typedef __attribute__((ext_vector_type(8))) short short8;
typedef __attribute__((ext_vector_type(4))) float floatx4;

static __device__ __forceinline__ unsigned short f2bf(float f) {
    return __builtin_bit_cast(unsigned short, (__bf16)f);
}

// ---------------------------------------------------------------------------
// Producer: blocks 0..1023: XW[e][bc*4+o][n] = bf16( sum_f x[bc][n][f] W[e][f][o] )
//           blocks 1024..1039: At[e][m][n] = bf16( A[e][n][m] / ||col m|| )
// 256 threads. Register-light: W staged in LDS, x row in 16 regs.
// ---------------------------------------------------------------------------
__global__ __launch_bounds__(256)
void produce_kernel(const float* __restrict__ x, const float* __restrict__ A,
                    const float* __restrict__ W,
                    unsigned short* __restrict__ XW, unsigned short* __restrict__ At) {
    __shared__ float Asub[128][33];   // prep path
    __shared__ float red[8][32];
    __shared__ float rnv[32];
    __shared__ float Wl[256];         // XW path: 4e x 16f x 4o

    const int t   = threadIdx.x;
    const int bid = blockIdx.x;

    if (bid >= 1024) {
        // ---------------- prep path (verified round 2) ----------------
        const int pb = bid - 1024;        // 0..15
        const int e  = pb >> 2;
        const int m0 = (pb & 3) * 32;
        const float* Ae = A + e * 16384 + m0;
        #pragma unroll
        for (int i = 0; i < 16; ++i) {
            int idx = t + i * 256;            // 0..4095
            int n = idx >> 5, ml = idx & 31;
            Asub[n][ml] = Ae[n * 128 + ml];   // coalesced in m
        }
        __syncthreads();
        {
            int ml = t & 31, g = t >> 5;
            float s = 0.f;
            #pragma unroll
            for (int j = 0; j < 16; ++j) {
                float v = Asub[g * 16 + j][ml];
                s += v * v;
            }
            red[g][ml] = s;
        }
        __syncthreads();
        if (t < 32) {
            float s = 0.f;
            #pragma unroll
            for (int g = 0; g < 8; ++g) s += red[g][t];
            rnv[t] = 1.0f / fmaxf(sqrtf(s), EPSN);
        }
        __syncthreads();
        {
            int ml = t >> 3;
            int n0 = (t & 7) * 16;
            float r = rnv[ml];
            unsigned short hs[16];
            #pragma unroll
            for (int j = 0; j < 16; ++j)
                hs[j] = f2bf(Asub[n0 + j][ml] * r);
            uint4* dst = (uint4*)(At + ((size_t)(e * 128 + m0 + ml) * 128 + n0));
            dst[0] = *(const uint4*)&hs[0];
            dst[1] = *(const uint4*)&hs[8];
        }
        return;
    }

    // ---------------- XW path ----------------
    if (t < 64) {
        float4 w4 = ((const float4*)W)[t];     // 256 floats, coalesced
        *(float4*)&Wl[t * 4] = w4;
    }

    const int bc = bid * 2 + (t >> 7);    // 2 bc per block
    const int n  = t & 127;
    const float4* xp = (const float4*)(x + ((size_t)bc * 128 + n) * 16);
    float xs[16];
    #pragma unroll
    for (int q = 0; q < 4; ++q) {
        float4 v = xp[q];
        xs[q * 4 + 0] = v.x; xs[q * 4 + 1] = v.y;
        xs[q * 4 + 2] = v.z; xs[q * 4 + 3] = v.w;
    }
    __syncthreads();

    #pragma unroll 1
    for (int e = 0; e < 4; ++e) {
        float a0 = 0.f, a1 = 0.f, a2 = 0.f, a3 = 0.f;
        #pragma unroll
        for (int f = 0; f < 16; ++f) {
            float xv = xs[f];
            float4 w = *(const float4*)&Wl[(e * 16 + f) * 4];  // broadcast ds_read_b128
            a0 += xv * w.x; a1 += xv * w.y; a2 += xv * w.z; a3 += xv * w.w;
        }
        // XW[e][bc*4+o][n]; for fixed o lanes n are consecutive -> coalesced
        size_t base = ((size_t)e * 8192 + (size_t)bc * 4) * 128 + n;
        XW[base      ] = f2bf(a0);
        XW[base + 128] = f2bf(a1);
        XW[base + 256] = f2bf(a2);
        XW[base + 384] = f2bf(a3);
    }
}

// ---------------------------------------------------------------------------
// Main: pure MFMA streamer, no LDS, no phase-1.
// grid 1024 = (h = gid>>9) x (bc-group of 4). wave = e.
// afrag rows r=lr from XW[e][bc0*4+r][n] (n-contiguous b128 loads);
// bfrag from At[e][m][n]; D col=lr=m-offset, row=lg*4+j -> bc=bc0+lg, o=j.
// ---------------------------------------------------------------------------
__global__ __launch_bounds__(256)
void gemm_kernel(const unsigned short* __restrict__ XW,
                 const unsigned short* __restrict__ At,
                 float* __restrict__ out) {
    const int t   = threadIdx.x;
    const int gid = blockIdx.x;
    const int h   = gid >> 9;
    const int bc0 = (gid & 511) * 4;

    const int e  = t >> 6;
    const int l  = t & 63;
    const int lr = l & 15;
    const int lg = l >> 4;

    const unsigned short* xwp = XW + ((size_t)e * 8192 + bc0 * 4 + lr) * 128 + lg * 8;
    const unsigned short* atp = At + (size_t)e * 16384 + (size_t)(h * 64 + lr) * 128 + lg * 8;

    bf16x8 af[4];
    #pragma unroll
    for (int ks = 0; ks < 4; ++ks)
        af[ks] = __builtin_bit_cast(bf16x8, *(const short8*)(xwp + ks * 32));

    bf16x8 bf[4][4];
    #pragma unroll
    for (int mt = 0; mt < 4; ++mt)
        #pragma unroll
        for (int ks = 0; ks < 4; ++ks)
            bf[mt][ks] = __builtin_bit_cast(bf16x8,
                *(const short8*)(atp + mt * 2048 + ks * 32));

    floatx4 acc[4];
    #pragma unroll
    for (int mt = 0; mt < 4; ++mt) acc[mt] = (floatx4){0.f, 0.f, 0.f, 0.f};

    #pragma unroll
    for (int mt = 0; mt < 4; ++mt)
        #pragma unroll
        for (int ks = 0; ks < 4; ++ks)
            acc[mt] = __builtin_amdgcn_mfma_f32_16x16x32_bf16(
                af[ks], bf[mt][ks], acc[mt], 0, 0, 0);

    const int bc = bc0 + lg, b = bc >> 4, c = bc & 15;
    float4* outp = (float4*)out + ((size_t)(b * 64 + e * 16 + c) * 128) + h * 64;
    #pragma unroll
    for (int mt = 0; mt < 4; ++mt) {
        float4 o4;
        o4.x = fmaxf(acc[mt][0], 0.f);
        o4.y = fmaxf(acc[mt][1], 0.f);
        o4.z = fmaxf(acc[mt][2], 0.f);
        o4.w = fmaxf(acc[mt][3], 0.f);
        outp[mt * 16 + lr] = o4;
    }
}

extern "C" void kernel_launch(void* const* d_in, const int* in_sizes, int n_in,
                              void* d_out, int out_size, void* d_ws, size_t ws_size,
                              hipStream_t stream) {
    const float* x = (const float*)d_in[0];   // [128,16,128,16]
    const float* A = (const float*)d_in[1];   // [4,128,128]
    const float* W = (const float*)d_in[2];   // [4,16,4]
    float* out = (float*)d_out;               // [128,64,128,4]
    unsigned short* At = (unsigned short*)d_ws;                   // 128 KB
    unsigned short* XW = (unsigned short*)((char*)d_ws + 131072); // 8.4 MB

    produce_kernel<<<1040, 256, 0, stream>>>(x, A, W, XW, At);
    gemm_kernel<<<1024, 256, 0, stream>>>(XW, At, out);
}

// Round 7
// 21.376 us; speedup vs baseline: 1.2683x; 1.2683x over previous
//
#include <hip/hip_runtime.h>
#include <math.h>

#define EPSN 1e-12f

typedef __attribute__((ext_vector_type(8))) __bf16 bf16x8;
typedef __attribute__((ext_vector_type(8))) short short8;
typedef __attribute__((ext_vector_type(4))) float floatx4;

static __device__ __forceinline__ unsigned short f2bf(float f) {
    return __builtin_bit_cast(unsigned short, (__bf16)f);
}

// ---------------------------------------------------------------------------
// Prep: At[e][m][n] = bf16( A[e][n][m] / max(||A[e][:][m]||_2, eps) )
// grid = 16 blocks (e in 0..3, m-chunk of 32), 256 threads  [verified round 2]
// ---------------------------------------------------------------------------
__global__ __launch_bounds__(256)
void prep_kernel(const float* __restrict__ A, unsigned short* __restrict__ At) {
    __shared__ float Asub[128][33];   // [n][m_local], padded
    __shared__ float red[8][32];
    __shared__ float rnv[32];
    const int t  = threadIdx.x;
    const int e  = blockIdx.x >> 2;
    const int m0 = (blockIdx.x & 3) * 32;
    const float* Ae = A + e * 16384 + m0;

    #pragma unroll
    for (int i = 0; i < 16; ++i) {
        int idx = t + i * 256;            // 0..4095
        int n = idx >> 5, ml = idx & 31;
        Asub[n][ml] = Ae[n * 128 + ml];   // coalesced in m
    }
    __syncthreads();
    {
        int ml = t & 31, g = t >> 5;
        float s = 0.f;
        #pragma unroll
        for (int j = 0; j < 16; ++j) {
            float v = Asub[g * 16 + j][ml];
            s += v * v;
        }
        red[g][ml] = s;
    }
    __syncthreads();
    if (t < 32) {
        float s = 0.f;
        #pragma unroll
        for (int g = 0; g < 8; ++g) s += red[g][t];
        rnv[t] = 1.0f / fmaxf(sqrtf(s), EPSN);
    }
    __syncthreads();
    {
        int ml = t >> 3;
        int n0 = (t & 7) * 16;
        float r = rnv[ml];
        unsigned short hs[16];
        #pragma unroll
        for (int j = 0; j < 16; ++j)
            hs[j] = f2bf(Asub[n0 + j][ml] * r);
        uint4* dst = (uint4*)(At + ((size_t)(e * 128 + m0 + ml) * 128 + n0));
        dst[0] = *(const uint4*)&hs[0];
        dst[1] = *(const uint4*)&hs[8];
    }
}

// ---------------------------------------------------------------------------
// Main: grid 512 = (m-half h = gid>>8) x (bc-group of 8 = gid&255).
// Phase 1: XW[e][r=(bcl,o)][n] = x@W -> LDS bf16 [4e][32r][128n], XOR-swizzled.
// Phase 2: wave e: 32 rows x 64 m, K=128 -> 32 MFMA per wave fed by only
//          16 B-fragment loads (2x better load:MFMA ratio than round 2).
// ---------------------------------------------------------------------------
__global__ __launch_bounds__(256, 4)
void gcn_mfma_kernel(const float* __restrict__ x, const float* __restrict__ W,
                     const unsigned short* __restrict__ At,
                     float* __restrict__ out) {
    __shared__ __align__(16) unsigned char xw[32768];  // 4e x 32r x 128n bf16, swizzled

    const int t   = threadIdx.x;
    const int gid = blockIdx.x;
    const int h   = gid >> 8;          // m-half; blocks g, g+256 same XCD (256%8==0)
    const int bc0 = (gid & 255) * 8;

    // ---- phase 1: each thread handles 4 (bc_local, n) pairs ----
    float4 xf[4][4];
    #pragma unroll
    for (int p = 0; p < 4; ++p) {
        int pair = p * 256 + t;           // 0..1023
        int bcl = pair >> 7, n = pair & 127;
        const float4* xp = (const float4*)(x + ((size_t)(bc0 + bcl) * 128 + n) * 16);
        xf[p][0] = xp[0]; xf[p][1] = xp[1]; xf[p][2] = xp[2]; xf[p][3] = xp[3];
    }
    const int nn = t & 127;
    #pragma unroll 1
    for (int e = 0; e < 4; ++e) {
        float4 We[16];                    // wave-uniform -> scalar loads
        const float4* wp = (const float4*)(W + e * 64);
        #pragma unroll
        for (int f = 0; f < 16; ++f) We[f] = wp[f];
        #pragma unroll
        for (int p = 0; p < 4; ++p) {
            float a0 = 0.f, a1 = 0.f, a2 = 0.f, a3 = 0.f;
            #pragma unroll
            for (int f = 0; f < 16; ++f) {
                float xv = ((const float*)&xf[p][f >> 2])[f & 3];
                a0 += xv * We[f].x; a1 += xv * We[f].y;
                a2 += xv * We[f].z; a3 += xv * We[f].w;
            }
            float av[4] = {a0, a1, a2, a3};
            int bcl = p * 2 + (t >> 7);
            #pragma unroll
            for (int o = 0; o < 4; ++o) {
                int r = bcl * 4 + o;
                int byteoff = (((e * 32 + r) << 8) + (nn << 1)) ^ ((r & 7) << 4);
                *(unsigned short*)(xw + byteoff) = f2bf(av[o]);
            }
        }
    }
    __syncthreads();

    // ---- phase 2: wave = e; GEMM 32r x 64m (half h), K=128 ----
    const int e  = t >> 6;
    const int l  = t & 63;
    const int lr = l & 15;    // A row offset / B col m-offset
    const int lg = l >> 4;    // k-group

    bf16x8 afrag[2][4];
    #pragma unroll
    for (int rt = 0; rt < 2; ++rt) {
        #pragma unroll
        for (int ks = 0; ks < 4; ++ks) {
            int row = rt * 16 + lr;
            int n0 = ks * 32 + lg * 8;
            int byteoff = (((e * 32 + row) << 8) + (n0 << 1)) ^ ((row & 7) << 4);
            afrag[rt][ks] = __builtin_bit_cast(bf16x8, *(const short8*)(xw + byteoff));
        }
    }

    floatx4 acc[2][4];
    #pragma unroll
    for (int rt = 0; rt < 2; ++rt)
        #pragma unroll
        for (int mt = 0; mt < 4; ++mt)
            acc[rt][mt] = (floatx4){0.f, 0.f, 0.f, 0.f};

    const unsigned short* Ate = At + (size_t)e * 16384 + (size_t)h * 64 * 128;
    #pragma unroll
    for (int mt = 0; mt < 4; ++mt) {
        int m = mt * 16 + lr;
        bf16x8 bfrag[4];
        #pragma unroll
        for (int ks = 0; ks < 4; ++ks) {
            short8 v = *(const short8*)(Ate + (size_t)m * 128 + ks * 32 + lg * 8);
            bfrag[ks] = __builtin_bit_cast(bf16x8, v);
        }
        #pragma unroll
        for (int ks = 0; ks < 4; ++ks) {
            acc[0][mt] = __builtin_amdgcn_mfma_f32_16x16x32_bf16(
                afrag[0][ks], bfrag[ks], acc[0][mt], 0, 0, 0);
            acc[1][mt] = __builtin_amdgcn_mfma_f32_16x16x32_bf16(
                afrag[1][ks], bfrag[ks], acc[1][mt], 0, 0, 0);
        }
    }

    // ---- epilogue: D col=lr (m-offset); row=lg*4+j -> r=rt*16+lg*4+j
    //      -> bcl = rt*4+lg, o=j.  Coalesced float4 stores.
    #pragma unroll
    for (int rt = 0; rt < 2; ++rt) {
        int bc = bc0 + rt * 4 + lg;
        int b = bc >> 4, c = bc & 15;
        float4* outp = (float4*)out + ((size_t)(b * 64 + e * 16 + c) * 128) + h * 64;
        #pragma unroll
        for (int mt = 0; mt < 4; ++mt) {
            float4 o4;
            o4.x = fmaxf(acc[rt][mt][0], 0.f);
            o4.y = fmaxf(acc[rt][mt][1], 0.f);
            o4.z = fmaxf(acc[rt][mt][2], 0.f);
            o4.w = fmaxf(acc[rt][mt][3], 0.f);
            outp[mt * 16 + lr] = o4;
        }
    }
}

extern "C" void kernel_launch(void* const* d_in, const int* in_sizes, int n_in,
                              void* d_out, int out_size, void* d_ws, size_t ws_size,
                              hipStream_t stream) {
    const float* x = (const float*)d_in[0];   // [128,16,128,16]
    const float* A = (const float*)d_in[1];   // [4,128,128]
    const float* W = (const float*)d_in[2];   // [4,16,4]
    float* out = (float*)d_out;               // [128,64,128,4]
    unsigned short* At = (unsigned short*)d_ws;  // 4*128*128 bf16 = 128 KB

    prep_kernel<<<16, 256, 0, stream>>>(A, At);
    gcn_mfma_kernel<<<512, 256, 0, stream>>>(x, W, At, out);
}